// Round 1
// baseline (416.808 us; speedup 1.0000x reference)
//
#include <hip/hip_runtime.h>
#include <math.h>

#define B_  64
#define N_  1024
#define M_  80
#define C1_ 288
#define D_  256
#define EPS_ 1e-12f

// ---------------- Kernel 1: per-batch attention pooling ----------------
// softmax(score, axis=m) is invariant to the (oa@w_o)[b,n]+ba shift (constant
// along m), so att depends only on b:  att_feat[b,d] = sum_m p[b,m]*lang[b,m,d]
__global__ __launch_bounds__(256) void prep_kernel(
    const float* __restrict__ lang_feat,   // B*M*D
    const int*   __restrict__ lang_mask,   // B*M
    const float* __restrict__ Wa,          // 2D x 1
    float* __restrict__ att_ws)            // B*D (workspace)
{
    __shared__ float wl_s[D_];
    __shared__ float ls[M_];
    const int b   = blockIdx.x;
    const int tid = threadIdx.x;

    wl_s[tid] = Wa[D_ + tid];              // w_l = Wa[D:, 0]
    __syncthreads();

    const int wave = tid >> 6, lane = tid & 63;
    for (int m = wave; m < M_; m += 4) {
        const float* lf = lang_feat + (size_t)(b * M_ + m) * D_;
        float p = 0.f;
        #pragma unroll
        for (int j = 0; j < 4; ++j) { int d = lane + 64 * j; p = fmaf(lf[d], wl_s[d], p); }
        #pragma unroll
        for (int off = 32; off; off >>= 1) p += __shfl_xor(p, off);
        if (lane == 0) ls[m] = (lang_mask[b * M_ + m] == 0) ? -INFINITY : p;
    }
    __syncthreads();

    float mx = -INFINITY;
    for (int m = 0; m < M_; ++m) mx = fmaxf(mx, ls[m]);
    __syncthreads();
    if (tid < M_) ls[tid] = expf(ls[tid] - mx);   // exp(-inf)=0 for masked
    __syncthreads();

    float sm = 0.f;
    for (int m = 0; m < M_; ++m) sm += ls[m];

    const int d = tid;
    float acc = 0.f;
    for (int m = 0; m < M_; ++m)
        acc = fmaf(ls[m], lang_feat[(size_t)(b * M_ + m) * D_ + d], acc);
    att_ws[b * D_ + d] = acc / sm;
}

// ---------------- Kernel 2: fused  relu(obj@W3+b3)@W4+b4  + epilogue ----------------
// Per 64-row tile (all rows share batch b since 64 | 1024):
//   Phase A: stage obj tile (64x288) in LDS (padded stride 292)
//   Phase B: GEMM1 -> relu -> LDS (reuse same buffer, stride 260)
//   Phase C: GEMM2 -> osc in registers
//   Phase D: x=relu(att_feat[b]*osc); out = (x . Ws)/max(||x||,eps) + bs
#define TR   64
#define LDO  292   // 288+4 pad (breaks 288%32==0 bank aliasing)
#define LDR  260   // 256+4 pad
#define RPT  4     // rows per thread (512 threads: 16 row-groups x 32 col-groups)

__global__ __launch_bounds__(512) void main_kernel(
    const float* __restrict__ obj,     // B*N*C1
    const float* __restrict__ W3,      // C1 x D
    const float* __restrict__ b3,      // D
    const float* __restrict__ W4,      // D x D
    const float* __restrict__ b4,      // D
    const float* __restrict__ Ws,      // D
    const float* __restrict__ bs,      // 1
    const float* __restrict__ att_ws,  // B*D
    float* __restrict__ out)           // B*N  (== flat row index)
{
    extern __shared__ float smem[];    // max(64*292, 64*260) floats = 74752 B
    const int tid = threadIdx.x;
    const int r0  = blockIdx.x * TR;
    const int b   = r0 >> 10;          // N_ = 1024

    // ---- Phase A: load obj tile as float4, fully coalesced ----
    {
        const float4* src = (const float4*)(obj + (size_t)r0 * C1_);
        const int NF4 = C1_ / 4;                       // 72 float4 per row
        for (int i = tid; i < TR * NF4; i += 512) {
            int row = i / NF4;
            int c4  = i - row * NF4;
            float4 v = src[i];
            *(float4*)&smem[row * LDO + c4 * 4] = v;
        }
    }
    __syncthreads();

    const int cid  = tid & 31;         // 32 col-groups * 8 cols
    const int rid  = tid >> 5;         // 16 row-groups * 4 rows
    const int col0 = cid * 8;

    float acc[RPT][8];
    {
        float binit[8];
        #pragma unroll
        for (int ci = 0; ci < 8; ++ci) binit[ci] = b3[col0 + ci];
        #pragma unroll
        for (int ri = 0; ri < RPT; ++ri)
            #pragma unroll
            for (int ci = 0; ci < 8; ++ci) acc[ri][ci] = binit[ci];
    }

    // ---- Phase B: GEMM1 (K=288) ----
    for (int k = 0; k < C1_; k += 4) {
        float4 a[RPT];
        #pragma unroll
        for (int ri = 0; ri < RPT; ++ri)
            a[ri] = *(const float4*)&smem[(rid * RPT + ri) * LDO + k];
        #pragma unroll
        for (int kk = 0; kk < 4; ++kk) {
            const float* wrow = &W3[(size_t)(k + kk) * D_ + col0];
            float4 w0 = *(const float4*)(wrow);
            float4 w1 = *(const float4*)(wrow + 4);
            float w[8] = {w0.x, w0.y, w0.z, w0.w, w1.x, w1.y, w1.z, w1.w};
            #pragma unroll
            for (int ri = 0; ri < RPT; ++ri) {
                float av = (kk == 0) ? a[ri].x : (kk == 1) ? a[ri].y
                         : (kk == 2) ? a[ri].z : a[ri].w;
                #pragma unroll
                for (int ci = 0; ci < 8; ++ci)
                    acc[ri][ci] = fmaf(av, w[ci], acc[ri][ci]);
            }
        }
    }

    // ---- relu -> LDS (reuse buffer; all obj reads are done) ----
    __syncthreads();
    #pragma unroll
    for (int ri = 0; ri < RPT; ++ri) {
        float4 v0, v1;
        v0.x = fmaxf(acc[ri][0], 0.f); v0.y = fmaxf(acc[ri][1], 0.f);
        v0.z = fmaxf(acc[ri][2], 0.f); v0.w = fmaxf(acc[ri][3], 0.f);
        v1.x = fmaxf(acc[ri][4], 0.f); v1.y = fmaxf(acc[ri][5], 0.f);
        v1.z = fmaxf(acc[ri][6], 0.f); v1.w = fmaxf(acc[ri][7], 0.f);
        *(float4*)&smem[(rid * RPT + ri) * LDR + col0]     = v0;
        *(float4*)&smem[(rid * RPT + ri) * LDR + col0 + 4] = v1;
    }
    __syncthreads();

    // ---- Phase C: GEMM2 (K=256) ----
    {
        float binit[8];
        #pragma unroll
        for (int ci = 0; ci < 8; ++ci) binit[ci] = b4[col0 + ci];
        #pragma unroll
        for (int ri = 0; ri < RPT; ++ri)
            #pragma unroll
            for (int ci = 0; ci < 8; ++ci) acc[ri][ci] = binit[ci];
    }
    for (int k = 0; k < D_; k += 4) {
        float4 a[RPT];
        #pragma unroll
        for (int ri = 0; ri < RPT; ++ri)
            a[ri] = *(const float4*)&smem[(rid * RPT + ri) * LDR + k];
        #pragma unroll
        for (int kk = 0; kk < 4; ++kk) {
            const float* wrow = &W4[(size_t)(k + kk) * D_ + col0];
            float4 w0 = *(const float4*)(wrow);
            float4 w1 = *(const float4*)(wrow + 4);
            float w[8] = {w0.x, w0.y, w0.z, w0.w, w1.x, w1.y, w1.z, w1.w};
            #pragma unroll
            for (int ri = 0; ri < RPT; ++ri) {
                float av = (kk == 0) ? a[ri].x : (kk == 1) ? a[ri].y
                         : (kk == 2) ? a[ri].z : a[ri].w;
                #pragma unroll
                for (int ci = 0; ci < 8; ++ci)
                    acc[ri][ci] = fmaf(av, w[ci], acc[ri][ci]);
            }
        }
    }

    // ---- Phase D: epilogue ----
    float af[8], wsv[8];
    #pragma unroll
    for (int ci = 0; ci < 8; ++ci) {
        af[ci]  = att_ws[b * D_ + col0 + ci];
        wsv[ci] = Ws[col0 + ci];
    }
    const float bsv = bs[0];

    #pragma unroll
    for (int ri = 0; ri < RPT; ++ri) {
        float s2 = 0.f, sw = 0.f;
        #pragma unroll
        for (int ci = 0; ci < 8; ++ci) {
            float x = fmaxf(af[ci] * acc[ri][ci], 0.f);
            s2 = fmaf(x, x, s2);
            sw = fmaf(x, wsv[ci], sw);
        }
        // reduce across the 32 col-group lanes (stays within half-wave)
        #pragma unroll
        for (int off = 1; off < 32; off <<= 1) {
            s2 += __shfl_xor(s2, off);
            sw += __shfl_xor(sw, off);
        }
        if (cid == 0) {
            float nrm = sqrtf(s2);
            out[r0 + rid * RPT + ri] = sw / fmaxf(nrm, EPS_) + bsv;
        }
    }
}

extern "C" void kernel_launch(void* const* d_in, const int* in_sizes, int n_in,
                              void* d_out, int out_size, void* d_ws, size_t ws_size,
                              hipStream_t stream) {
    const float* object_feat = (const float*)d_in[0];
    const float* lang_feat   = (const float*)d_in[1];
    const int*   lang_mask   = (const int*)d_in[2];
    // d_in[3..8] = W1,b1,W2,b2,Wa,ba : W1/b1/W2/b2/ba are dead (softmax shift
    // invariance along axis m kills the object-score branch entirely).
    const float* Wa = (const float*)d_in[7];
    const float* W3 = (const float*)d_in[9];
    const float* b3 = (const float*)d_in[10];
    const float* W4 = (const float*)d_in[11];
    const float* b4 = (const float*)d_in[12];
    const float* Ws = (const float*)d_in[13];
    const float* bs = (const float*)d_in[14];
    float* out    = (float*)d_out;
    float* att_ws = (float*)d_ws;   // B*D floats = 64 KB

    prep_kernel<<<B_, 256, 0, stream>>>(lang_feat, lang_mask, Wa, att_ws);

    const int smem_bytes = TR * LDO * sizeof(float);   // 74752 B
    main_kernel<<<(B_ * N_) / TR, 512, smem_bytes, stream>>>(
        object_feat, W3, b3, W4, b4, Ws, bs, att_ws, out);
}

// Round 2
// 173.912 us; speedup vs baseline: 2.3967x; 2.3967x over previous
//
#include <hip/hip_runtime.h>
#include <math.h>
#include <stdint.h>

#define B_  64
#define N_  1024
#define M_  80
#define C1_ 288
#define D_  256
#define EPS_ 1e-12f

typedef _Float16 f16;
typedef _Float16 f16x8 __attribute__((ext_vector_type(8)));
typedef _Float16 f16x4 __attribute__((ext_vector_type(4)));
typedef float    f32x4 __attribute__((ext_vector_type(4)));

// workspace layout (bytes)
#define ATT_OFF 0                       // 64*256 f32   = 65536
#define W3F_OFF 65536                   // 9 ksteps * 16384 B = 147456
#define W4F_OFF (65536 + 147456)        // 8 ksteps * 16384 B = 131072
// total = 344064 B

// ---------------- Kernel 1: per-batch attention pooling (fp32) ----------------
// softmax(score, axis=m) is invariant to the (oa@w_o)[b,n]+ba shift, so att
// depends only on b: att[b,d] = sum_m softmax(lang@w_l + mask)[m] * lang[b,m,d]
__global__ __launch_bounds__(256) void prep_kernel(
    const float* __restrict__ lang_feat,   // B*M*D
    const int*   __restrict__ lang_mask,   // B*M
    const float* __restrict__ Wa,          // 2D x 1
    float* __restrict__ att_ws)            // B*D
{
    __shared__ float wl_s[D_];
    __shared__ float ls[M_];
    const int b   = blockIdx.x;
    const int tid = threadIdx.x;

    wl_s[tid] = Wa[D_ + tid];
    __syncthreads();

    const int wave = tid >> 6, lane = tid & 63;
    for (int m = wave; m < M_; m += 4) {
        const float* lf = lang_feat + (size_t)(b * M_ + m) * D_;
        float p = 0.f;
        #pragma unroll
        for (int j = 0; j < 4; ++j) { int d = lane + 64 * j; p = fmaf(lf[d], wl_s[d], p); }
        #pragma unroll
        for (int off = 32; off; off >>= 1) p += __shfl_xor(p, off);
        if (lane == 0) ls[m] = (lang_mask[b * M_ + m] == 0) ? -INFINITY : p;
    }
    __syncthreads();

    float mx = -INFINITY;
    for (int m = 0; m < M_; ++m) mx = fmaxf(mx, ls[m]);
    __syncthreads();
    if (tid < M_) ls[tid] = expf(ls[tid] - mx);
    __syncthreads();

    float sm = 0.f;
    for (int m = 0; m < M_; ++m) sm += ls[m];

    const int d = tid;
    float acc = 0.f;
    for (int m = 0; m < M_; ++m)
        acc = fmaf(ls[m], lang_feat[(size_t)(b * M_ + m) * D_ + d], acc);
    att_ws[b * D_ + d] = acc / sm;
}

// ---------------- Kernel 2: W3/W4 -> f16 MFMA B-fragment layout ----------------
// Frag layout per kstep plane (16384 B): [nt(16)][lane(64)][i(8)] f16, where
// element = W[k][col], k = kstep*32 + (lane>>4)*8 + i, col = nt*16 + (lane&15).
__global__ __launch_bounds__(256) void wprep_kernel(
    const float* __restrict__ W3, const float* __restrict__ W4,
    f16* __restrict__ w3f, f16* __restrict__ w4f)
{
    const int kb = blockIdx.x;
    const float* src; f16* dst; int K0;
    if (kb < 9) { src = W3; dst = w3f + kb * 8192;      K0 = kb * 32; }
    else        { src = W4; dst = w4f + (kb - 9) * 8192; K0 = (kb - 9) * 32; }
    for (int idx = threadIdx.x; idx < 8192; idx += 256) {
        int nt  = idx >> 9;
        int rem = idx & 511;
        int ln  = rem >> 3;
        int i   = rem & 7;
        int k   = K0 + ((ln >> 4) << 3) + i;
        int col = (nt << 4) + (ln & 15);
        dst[idx] = (f16)src[k * D_ + col];
    }
}

// ---------------- Kernel 3: fused MFMA GEMM-GEMM + epilogue ----------------
__device__ __forceinline__ void g2l16(const void* g, void* l) {
    __builtin_amdgcn_global_load_lds(
        (const __attribute__((address_space(1))) uint32_t*)g,
        (__attribute__((address_space(3))) uint32_t*)l, 16, 0, 0);
}

#define ABYTES 36864          // A frags: 4 mt * 9 ks * 1024 B (h3 frags reuse: 4*8*1024)
#define BBUF   16384          // one B kstep plane

__global__ __launch_bounds__(512) void main_kernel(
    const float* __restrict__ obj,     // B*N*C1 fp32
    const f16*  __restrict__ w3f,      // 9 kstep planes
    const f16*  __restrict__ w4f,      // 8 kstep planes
    const float* __restrict__ b3,
    const float* __restrict__ b4,
    const float* __restrict__ Ws,
    const float* __restrict__ bs,
    const float* __restrict__ att,     // B*D fp32
    float* __restrict__ out)           // B*N
{
    extern __shared__ char smem[];
    char* Areg = smem;                 // 36864 B
    char* Breg = smem + ABYTES;        // 2 * 16384 B

    const int tid  = threadIdx.x;
    const int lane = tid & 63;
    const int w    = tid >> 6;         // 8 waves
    const int mt   = w & 3;            // row-tile (16 rows)
    const int ng   = w >> 2;           // col half (128 cols)
    const int r0   = blockIdx.x * 64;
    const int b    = blockIdx.x >> 4;  // 16 blocks per batch

    // ---- Stage A: obj tile fp32 -> f16 fragments in LDS ----
    // element (row,c) -> plane (row>>4)*9+(c>>5), slot lane2*16 + (c&7)*2,
    // lane2 = (row&15) + 16*((c&31)>>3). float4 (c%4==0) stays in one 8B slot.
    {
        const float4* src = (const float4*)(obj + (size_t)r0 * C1_);
        for (int idx = tid; idx < 64 * 72; idx += 512) {
            int row = idx / 72;
            int c   = (idx - row * 72) * 4;
            float4 v = src[idx];
            int plane = (row >> 4) * 9 + (c >> 5);
            int lane2 = (row & 15) + (((c & 31) >> 3) << 4);
            int ii    = c & 7;
            f16x4 h = { (f16)v.x, (f16)v.y, (f16)v.z, (f16)v.w };
            *(f16x4*)&Areg[plane * 1024 + lane2 * 16 + ii * 2] = h;
        }
    }

    const int colbase = (ng << 7) + (lane & 15);   // + nt*16

    f32x4 acc[8];
    #pragma unroll
    for (int nt = 0; nt < 8; ++nt) {
        float bv = b3[colbase + (nt << 4)];
        acc[nt] = (f32x4){bv, bv, bv, bv};
    }

    // prologue: stage B kstep 0 into buf0 (2 frags per wave = 16 total)
    {
        const char* g = (const char*)w3f + (w * 2) * 1024 + lane * 16;
        char* l = Breg + (w * 2) * 1024;
        g2l16(g, l); g2l16(g + 1024, l + 1024);
    }
    __syncthreads();   // drains vmcnt (B stage) + lgkm (A writes)

    // ---- GEMM1: h3 = relu(obj @ W3 + b3), K=288 (9 ksteps) ----
    for (int ks = 0; ks < 9; ++ks) {
        if (ks < 8) {
            const char* g = (const char*)w3f + (ks + 1) * BBUF + (w * 2) * 1024 + lane * 16;
            char* l = Breg + ((ks + 1) & 1) * BBUF + (w * 2) * 1024;
            g2l16(g, l); g2l16(g + 1024, l + 1024);
        }
        f16x8 a = *(const f16x8*)&Areg[(mt * 9 + ks) * 1024 + lane * 16];
        const char* bb = Breg + (ks & 1) * BBUF + (ng << 13);
        #pragma unroll
        for (int nt = 0; nt < 8; ++nt) {
            f16x8 bf = *(const f16x8*)&bb[nt * 1024 + lane * 16];
            acc[nt] = __builtin_amdgcn_mfma_f32_16x16x32_f16(a, bf, acc[nt], 0, 0, 0);
        }
        __syncthreads();
    }

    // ---- relu(h3) -> LDS in GEMM2-A-fragment layout (overwrites A region) ----
    // C/D layout: col=lane&15, row=(lane>>4)*4+reg  [m89]
    #pragma unroll
    for (int nt = 0; nt < 8; ++nt) {
        int colg  = colbase + (nt << 4);
        int plane = (mt << 3) + (colg >> 5);
        int l2b   = (((colg & 31) >> 3) << 4);
        int i2    = colg & 7;
        #pragma unroll
        for (int r = 0; r < 4; ++r) {
            int row_l = ((lane >> 4) << 2) + r;
            *(f16*)&Areg[plane * 1024 + (l2b + row_l) * 16 + i2 * 2] = (f16)fmaxf(acc[nt][r], 0.f);
        }
    }

    #pragma unroll
    for (int nt = 0; nt < 8; ++nt) {
        float bv = b4[colbase + (nt << 4)];
        acc[nt] = (f32x4){bv, bv, bv, bv};
    }
    {
        const char* g = (const char*)w4f + (w * 2) * 1024 + lane * 16;
        char* l = Breg + (w * 2) * 1024;
        g2l16(g, l); g2l16(g + 1024, l + 1024);
    }
    __syncthreads();   // h3 writes + B stage drained

    // ---- GEMM2: osc = h3 @ W4 + b4, K=256 (8 ksteps) ----
    for (int ks = 0; ks < 8; ++ks) {
        if (ks < 7) {
            const char* g = (const char*)w4f + (ks + 1) * BBUF + (w * 2) * 1024 + lane * 16;
            char* l = Breg + ((ks + 1) & 1) * BBUF + (w * 2) * 1024;
            g2l16(g, l); g2l16(g + 1024, l + 1024);
        }
        f16x8 a = *(const f16x8*)&Areg[(mt * 8 + ks) * 1024 + lane * 16];
        const char* bb = Breg + (ks & 1) * BBUF + (ng << 13);
        #pragma unroll
        for (int nt = 0; nt < 8; ++nt) {
            f16x8 bf = *(const f16x8*)&bb[nt * 1024 + lane * 16];
            acc[nt] = __builtin_amdgcn_mfma_f32_16x16x32_f16(a, bf, acc[nt], 0, 0, 0);
        }
        __syncthreads();
    }

    // ---- Epilogue (fp32): x=relu(att*osc); out = (x.Ws)/max(||x||,eps) + bs ----
    const float bsv = bs[0];
    float s2r[4] = {0, 0, 0, 0}, swr[4] = {0, 0, 0, 0};
    #pragma unroll
    for (int nt = 0; nt < 8; ++nt) {
        int colg = colbase + (nt << 4);
        float av = att[(b << 8) + colg];
        float wv = Ws[colg];
        #pragma unroll
        for (int r = 0; r < 4; ++r) {
            float x = fmaxf(av * acc[nt][r], 0.f);
            s2r[r] = fmaf(x, x, s2r[r]);
            swr[r] = fmaf(x, wv, swr[r]);
        }
    }
    #pragma unroll
    for (int off = 1; off < 16; off <<= 1) {
        #pragma unroll
        for (int r = 0; r < 4; ++r) {
            s2r[r] += __shfl_xor(s2r[r], off);
            swr[r] += __shfl_xor(swr[r], off);
        }
    }
    float* red = (float*)Breg;   // 64 rows * 2 f32 = 512 B, Breg is free now
    if (ng == 0 && (lane & 15) == 0) {
        #pragma unroll
        for (int r = 0; r < 4; ++r) {
            int row = (mt << 4) + ((lane >> 4) << 2) + r;
            red[row * 2]     = s2r[r];
            red[row * 2 + 1] = swr[r];
        }
    }
    __syncthreads();
    if (ng == 1 && (lane & 15) == 0) {
        #pragma unroll
        for (int r = 0; r < 4; ++r) {
            int row = (mt << 4) + ((lane >> 4) << 2) + r;
            float S2 = s2r[r] + red[row * 2];
            float SW = swr[r] + red[row * 2 + 1];
            out[r0 + row] = SW / fmaxf(sqrtf(S2), EPS_) + bsv;
        }
    }
}

extern "C" void kernel_launch(void* const* d_in, const int* in_sizes, int n_in,
                              void* d_out, int out_size, void* d_ws, size_t ws_size,
                              hipStream_t stream) {
    const float* object_feat = (const float*)d_in[0];
    const float* lang_feat   = (const float*)d_in[1];
    const int*   lang_mask   = (const int*)d_in[2];
    // d_in[3..6],[8] = W1,b1,W2,b2,ba : dead (softmax shift-invariance)
    const float* Wa = (const float*)d_in[7];
    const float* W3 = (const float*)d_in[9];
    const float* b3 = (const float*)d_in[10];
    const float* W4 = (const float*)d_in[11];
    const float* b4 = (const float*)d_in[12];
    const float* Ws = (const float*)d_in[13];
    const float* bs = (const float*)d_in[14];
    float* out = (float*)d_out;

    char* ws  = (char*)d_ws;             // needs 344064 B
    float* att = (float*)(ws + ATT_OFF);
    f16*  w3f = (f16*)(ws + W3F_OFF);
    f16*  w4f = (f16*)(ws + W4F_OFF);

    prep_kernel<<<B_, 256, 0, stream>>>(lang_feat, lang_mask, Wa, att);
    wprep_kernel<<<17, 256, 0, stream>>>(W3, W4, w3f, w4f);

    main_kernel<<<(B_ * N_) / 64, 512, ABYTES + 2 * BBUF, stream>>>(
        object_feat, w3f, w4f, b3, b4, Ws, bs, att, out);
}

// Round 3
// 171.625 us; speedup vs baseline: 2.4286x; 1.0133x over previous
//
#include <hip/hip_runtime.h>
#include <math.h>
#include <stdint.h>

#define B_  64
#define N_  1024
#define M_  80
#define C1_ 288
#define D_  256
#define EPS_ 1e-12f

typedef _Float16 f16;
typedef _Float16 f16x8 __attribute__((ext_vector_type(8)));
typedef float    f32x4 __attribute__((ext_vector_type(4)));

// workspace layout (bytes)
#define ATT_OFF 0                        // 64*256*4      = 65536
#define W3F_OFF 65536                    // 9 planes *16KB = 147456
#define W4F_OFF (65536 + 147456)         // 8 planes *16KB = 131072
#define H3_OFF  (65536 + 147456 + 131072)// 65536*256*2    = 33554432
// total ~33.9 MB

__device__ __forceinline__ void g2l16(const void* g, void* l) {
    __builtin_amdgcn_global_load_lds(
        (const __attribute__((address_space(1))) uint32_t*)g,
        (__attribute__((address_space(3))) uint32_t*)l, 16, 0, 0);
}

// ---------------- Kernel 1: prep (att pooling) + W3/W4 fragment repack ----------------
// softmax(score, axis=m) is invariant to the (oa@w_o)[b,n]+ba shift, so att
// depends only on b. Blocks 0..63: att. Blocks 64..80: repack one 32-deep
// kstep plane of W3/W4 into MFMA B-fragment order:
//   plane[nt][lane][i] = W[ks*32 + (lane>>4)*8 + i][nt*16 + (lane&15)]
__global__ __launch_bounds__(256) void prep_kernel(
    const float* __restrict__ lang_feat,   // B*M*D
    const int*   __restrict__ lang_mask,   // B*M
    const float* __restrict__ Wa,          // 2D x 1
    const float* __restrict__ W3,
    const float* __restrict__ W4,
    float* __restrict__ att_ws,            // B*D
    f16* __restrict__ w3f, f16* __restrict__ w4f)
{
    const int bi = blockIdx.x;
    if (bi >= B_) {
        const int kb = bi - B_;
        const float* src; f16* dst; int K0;
        if (kb < 9) { src = W3; dst = w3f + kb * 8192;       K0 = kb * 32; }
        else        { src = W4; dst = w4f + (kb - 9) * 8192; K0 = (kb - 9) * 32; }
        for (int idx = threadIdx.x; idx < 8192; idx += 256) {
            int nt  = idx >> 9;
            int rem = idx & 511;
            int ln  = rem >> 3;
            int i   = rem & 7;
            int k   = K0 + ((ln >> 4) << 3) + i;
            int col = (nt << 4) + (ln & 15);
            dst[idx] = (f16)src[k * D_ + col];
        }
        return;
    }

    __shared__ float wl_s[D_];
    __shared__ float ls[M_];
    const int b   = bi;
    const int tid = threadIdx.x;

    wl_s[tid] = Wa[D_ + tid];
    __syncthreads();

    const int wave = tid >> 6, lane = tid & 63;
    for (int m = wave; m < M_; m += 4) {
        const float* lf = lang_feat + (size_t)(b * M_ + m) * D_;
        float p = 0.f;
        #pragma unroll
        for (int j = 0; j < 4; ++j) { int d = lane + 64 * j; p = fmaf(lf[d], wl_s[d], p); }
        #pragma unroll
        for (int off = 32; off; off >>= 1) p += __shfl_xor(p, off);
        if (lane == 0) ls[m] = (lang_mask[b * M_ + m] == 0) ? -INFINITY : p;
    }
    __syncthreads();

    float mx = -INFINITY;
    #pragma unroll
    for (int m0 = 0; m0 < M_; m0 += 8) {
        float v0 = ls[m0], v1 = ls[m0+1], v2 = ls[m0+2], v3 = ls[m0+3];
        float v4 = ls[m0+4], v5 = ls[m0+5], v6 = ls[m0+6], v7 = ls[m0+7];
        mx = fmaxf(mx, fmaxf(fmaxf(fmaxf(v0,v1), fmaxf(v2,v3)),
                             fmaxf(fmaxf(v4,v5), fmaxf(v6,v7))));
    }
    __syncthreads();
    if (tid < M_) ls[tid] = expf(ls[tid] - mx);
    __syncthreads();

    float s0 = 0.f, s1 = 0.f, s2 = 0.f, s3 = 0.f;
    #pragma unroll
    for (int m0 = 0; m0 < M_; m0 += 8) {
        s0 += ls[m0] + ls[m0+4];
        s1 += ls[m0+1] + ls[m0+5];
        s2 += ls[m0+2] + ls[m0+6];
        s3 += ls[m0+3] + ls[m0+7];
    }
    const float inv = 1.f / ((s0 + s1) + (s2 + s3));

    const int d = tid;
    float a0 = 0.f, a1 = 0.f, a2 = 0.f, a3 = 0.f;
    const float* lfb = lang_feat + (size_t)b * M_ * D_ + d;
    #pragma unroll 5
    for (int m = 0; m < M_; m += 4) {
        a0 = fmaf(ls[m],   lfb[(size_t)m * D_],       a0);
        a1 = fmaf(ls[m+1], lfb[(size_t)(m+1) * D_],   a1);
        a2 = fmaf(ls[m+2], lfb[(size_t)(m+2) * D_],   a2);
        a3 = fmaf(ls[m+3], lfb[(size_t)(m+3) * D_],   a3);
    }
    att_ws[b * D_ + d] = ((a0 + a1) + (a2 + a3)) * inv;
}

// ---------------- Kernel 2: h3 = relu(obj @ W3 + b3) -> f16 ----------------
// W3f fully LDS-resident (147456 B). 256 blocks x 8 waves; each wave = one
// 32-row x 256-col tile. No barriers after the initial W3f stage.
__global__ __launch_bounds__(512, 2) void gemm1_kernel(
    const float* __restrict__ obj,     // B*N*C1 fp32
    const f16*  __restrict__ w3f,      // 9 fragment planes
    const float* __restrict__ b3,
    f16* __restrict__ h3)              // 65536 x 256 row-major f16
{
    extern __shared__ char smem[];     // 147456
    const int tid  = threadIdx.x;
    const int lane = tid & 63;
    const int w    = tid >> 6;

    #pragma unroll
    for (int i = 0; i < 18; ++i) {
        int off = (i * 512 + tid) * 16;
        g2l16((const char*)w3f + off, smem + off);
    }
    __syncthreads();

    const int r0   = (blockIdx.x * 8 + w) * 32;
    const int colc = lane & 15;
    const int kc   = (lane >> 4) << 3;     // 0,8,16,24

    f32x4 acc0[16], acc1[16];
    #pragma unroll
    for (int nt = 0; nt < 16; ++nt) {
        float bv = b3[(nt << 4) + colc];
        acc0[nt] = (f32x4){bv, bv, bv, bv};
        acc1[nt] = acc0[nt];
    }

    const float* arow0 = obj + (size_t)(r0 + colc) * C1_ + kc;
    const float* arow1 = arow0 + 16 * C1_;

    #pragma unroll 3
    for (int ks = 0; ks < 9; ++ks) {
        float4 p00 = *(const float4*)(arow0 + ks * 32);
        float4 p01 = *(const float4*)(arow0 + ks * 32 + 4);
        float4 p10 = *(const float4*)(arow1 + ks * 32);
        float4 p11 = *(const float4*)(arow1 + ks * 32 + 4);
        f16x8 a0 = {(f16)p00.x,(f16)p00.y,(f16)p00.z,(f16)p00.w,
                    (f16)p01.x,(f16)p01.y,(f16)p01.z,(f16)p01.w};
        f16x8 a1 = {(f16)p10.x,(f16)p10.y,(f16)p10.z,(f16)p10.w,
                    (f16)p11.x,(f16)p11.y,(f16)p11.z,(f16)p11.w};
        const char* bb = smem + ks * 16384;
        #pragma unroll
        for (int nt = 0; nt < 16; ++nt) {
            f16x8 bf = *(const f16x8*)&bb[nt * 1024 + lane * 16];
            acc0[nt] = __builtin_amdgcn_mfma_f32_16x16x32_f16(a0, bf, acc0[nt], 0, 0, 0);
            acc1[nt] = __builtin_amdgcn_mfma_f32_16x16x32_f16(a1, bf, acc1[nt], 0, 0, 0);
        }
    }

    // store relu(h3): C/D layout col=lane&15, row=(lane>>4)*4+r [m89]
    const int rbase = (lane >> 4) << 2;
    #pragma unroll
    for (int h = 0; h < 2; ++h) {
        #pragma unroll
        for (int r = 0; r < 4; ++r) {
            int row = r0 + 16 * h + rbase + r;
            f16* dst = h3 + (size_t)row * D_ + colc;
            #pragma unroll
            for (int nt = 0; nt < 16; ++nt) {
                f32x4 a = h ? acc1[nt] : acc0[nt];
                dst[nt << 4] = (f16)fmaxf(a[r], 0.f);
            }
        }
    }
}

// ---------------- Kernel 3: osc = h3 @ W4 + b4, fused epilogue ----------------
__global__ __launch_bounds__(512, 2) void gemm2_kernel(
    const f16*  __restrict__ h3,
    const f16*  __restrict__ w4f,      // 8 fragment planes
    const float* __restrict__ b4,
    const float* __restrict__ Ws,
    const float* __restrict__ bs,
    const float* __restrict__ att,     // B*D
    float* __restrict__ out)           // B*N
{
    extern __shared__ char smem[];     // 131072
    const int tid  = threadIdx.x;
    const int lane = tid & 63;
    const int w    = tid >> 6;

    #pragma unroll
    for (int i = 0; i < 16; ++i) {
        int off = (i * 512 + tid) * 16;
        g2l16((const char*)w4f + off, smem + off);
    }
    __syncthreads();

    const int r0   = (blockIdx.x * 8 + w) * 32;
    const int b    = r0 >> 10;
    const int colc = lane & 15;
    const int kcB  = (lane >> 4) << 3;

    f32x4 acc0[16], acc1[16];
    #pragma unroll
    for (int nt = 0; nt < 16; ++nt) {
        float bv = b4[(nt << 4) + colc];
        acc0[nt] = (f32x4){bv, bv, bv, bv};
        acc1[nt] = acc0[nt];
    }

    const f16* a0p = h3 + (size_t)(r0 + colc) * D_ + kcB;
    const f16* a1p = a0p + 16 * D_;

    #pragma unroll 4
    for (int ks = 0; ks < 8; ++ks) {
        f16x8 a0 = *(const f16x8*)(a0p + ks * 32);
        f16x8 a1 = *(const f16x8*)(a1p + ks * 32);
        const char* bb = smem + ks * 16384;
        #pragma unroll
        for (int nt = 0; nt < 16; ++nt) {
            f16x8 bf = *(const f16x8*)&bb[nt * 1024 + lane * 16];
            acc0[nt] = __builtin_amdgcn_mfma_f32_16x16x32_f16(a0, bf, acc0[nt], 0, 0, 0);
            acc1[nt] = __builtin_amdgcn_mfma_f32_16x16x32_f16(a1, bf, acc1[nt], 0, 0, 0);
        }
    }

    // epilogue: x=relu(att*osc); out=(x.Ws)/max(||x||,eps)+bs.
    // Wave owns all 256 cols -> 16-lane shfl reduce only.
    const float bsv = bs[0];
    float s20[4] = {0,0,0,0}, sw0[4] = {0,0,0,0};
    float s21[4] = {0,0,0,0}, sw1[4] = {0,0,0,0};
    #pragma unroll
    for (int nt = 0; nt < 16; ++nt) {
        int colg = (nt << 4) + colc;
        float av = att[(b << 8) + colg];
        float wv = Ws[colg];
        #pragma unroll
        for (int r = 0; r < 4; ++r) {
            float x0 = fmaxf(av * acc0[nt][r], 0.f);
            float x1 = fmaxf(av * acc1[nt][r], 0.f);
            s20[r] = fmaf(x0, x0, s20[r]);  sw0[r] = fmaf(x0, wv, sw0[r]);
            s21[r] = fmaf(x1, x1, s21[r]);  sw1[r] = fmaf(x1, wv, sw1[r]);
        }
    }
    #pragma unroll
    for (int off = 1; off < 16; off <<= 1) {
        #pragma unroll
        for (int r = 0; r < 4; ++r) {
            s20[r] += __shfl_xor(s20[r], off);  sw0[r] += __shfl_xor(sw0[r], off);
            s21[r] += __shfl_xor(s21[r], off);  sw1[r] += __shfl_xor(sw1[r], off);
        }
    }
    if (colc == 0) {
        const int rbase = (lane >> 4) << 2;
        #pragma unroll
        for (int r = 0; r < 4; ++r) {
            out[r0 + rbase + r]      = sw0[r] / fmaxf(sqrtf(s20[r]), EPS_) + bsv;
            out[r0 + 16 + rbase + r] = sw1[r] / fmaxf(sqrtf(s21[r]), EPS_) + bsv;
        }
    }
}

extern "C" void kernel_launch(void* const* d_in, const int* in_sizes, int n_in,
                              void* d_out, int out_size, void* d_ws, size_t ws_size,
                              hipStream_t stream) {
    const float* object_feat = (const float*)d_in[0];
    const float* lang_feat   = (const float*)d_in[1];
    const int*   lang_mask   = (const int*)d_in[2];
    // d_in[3..6],[8] = W1,b1,W2,b2,ba : dead (softmax shift-invariance)
    const float* Wa = (const float*)d_in[7];
    const float* W3 = (const float*)d_in[9];
    const float* b3 = (const float*)d_in[10];
    const float* W4 = (const float*)d_in[11];
    const float* b4 = (const float*)d_in[12];
    const float* Ws = (const float*)d_in[13];
    const float* bs = (const float*)d_in[14];
    float* out = (float*)d_out;

    char* ws   = (char*)d_ws;
    float* att = (float*)(ws + ATT_OFF);
    f16*  w3f  = (f16*)(ws + W3F_OFF);
    f16*  w4f  = (f16*)(ws + W4F_OFF);
    f16*  h3   = (f16*)(ws + H3_OFF);

    // dynamic LDS > 64KB needs the attribute (idempotent, host-side, capture-safe)
    hipFuncSetAttribute(reinterpret_cast<const void*>(gemm1_kernel),
                        hipFuncAttributeMaxDynamicSharedMemorySize, 147456);
    hipFuncSetAttribute(reinterpret_cast<const void*>(gemm2_kernel),
                        hipFuncAttributeMaxDynamicSharedMemorySize, 131072);

    prep_kernel<<<B_ + 17, 256, 0, stream>>>(lang_feat, lang_mask, Wa, W3, W4,
                                             att, w3f, w4f);
    gemm1_kernel<<<256, 512, 147456, stream>>>(object_feat, w3f, b3, h3);
    gemm2_kernel<<<256, 512, 131072, stream>>>(h3, w4f, b4, Ws, bs, att, out);
}